// Round 6
// baseline (119.767 us; speedup 1.0000x reference)
//
#include <hip/hip_runtime.h>

// Problem constants (fixed by setup_inputs).
#define B_     16
#define C_     3
#define H_     512
#define W_     1024
#define MW     256         // mask_width
#define RS     16          // output rows per strip
#define NSTRIP 32          // 32*16 = 512 exact (no ragged strip)
#define NIN    26          // RS + 10 input rows streamed per strip
#define NPAIR  13
#define NBLK   (B_ * C_ * NSTRIP)  // 1536 blocks

#define FENCE() do { __builtin_amdgcn_sched_barrier(0); \
                     __builtin_amdgcn_wave_barrier();   \
                     __builtin_amdgcn_sched_barrier(0); } while (0)

__global__ __launch_bounds__(256) void ssim_main(const float* __restrict__ img1,
                                                 const float* __restrict__ img2,
                                                 const int*   __restrict__ mask_pos,
                                                 float*       __restrict__ accum,
                                                 unsigned int* __restrict__ cnt,
                                                 float*       __restrict__ out) {
    // Gaussian weights = float64 exp/normalize, precomputed to float literals.
    constexpr float G[11] = {
        0.00102838f, 0.00759876f, 0.03600077f, 0.10936070f, 0.21300553f,
        0.26601173f, 0.21300553f, 0.10936070f, 0.03600077f, 0.00759876f,
        0.00102838f };

    // Per-wave QUAD-buffered 74-col {img1,img2} rows: read pair {i,i+1} while
    // writing pair {i+2,i+3} -> statically disjoint buffers, 1 fence per pair.
    __shared__ float2 rowbuf[4][4][80];
    __shared__ float  blksum[4];

    const int tid  = threadIdx.x;
    const int w    = tid >> 6;
    const int lane = tid & 63;

    const int blk   = blockIdx.x;
    const int strip = blk & (NSTRIP - 1);
    const int bc    = blk >> 5;          // (b,ch) 0..47
    const int b     = bc / 3;

    int s0 = mask_pos[b];
    s0 = min(max(s0, 0), W_ - MW);

    const float* __restrict__ p1 = img1 + (size_t)bc * (H_ * W_);
    const float* __restrict__ p2 = img2 + (size_t)bc * (H_ * W_);

    const int y0  = strip * RS;
    const int sx0 = w << 6;              // column strip base within crop
    const int cxm = sx0 - 5 + lane;      // main staged column (crop coords)
    const int cxh = sx0 + 59 + lane;     // halo staged column (lane < 10)
    const bool vm = (cxm >= 0) && (cxm < MW);
    const bool vh = (lane < 10) && (cxh < MW);
    const int gxm = s0 + cxm;
    const int gxh = s0 + cxh;

    // Two named prefetch register sets (even row / odd row of the next pair).
    float Aa0, Ab0, Aa1, Ab1;
    float Ba0, Bb0, Ba1, Bb1;

    auto loadA = [&](int r) {
        Aa0 = Ab0 = Aa1 = Ab1 = 0.f;
        if (r >= 0 && r < H_) {          // wave-uniform branch
            const int ro = r * W_;
            if (vm) { Aa0 = p1[ro + gxm]; Ab0 = p2[ro + gxm]; }
            if (vh) { Aa1 = p1[ro + gxh]; Ab1 = p2[ro + gxh]; }
        }
    };
    auto loadB = [&](int r) {
        Ba0 = Bb0 = Ba1 = Bb1 = 0.f;
        if (r >= 0 && r < H_) {
            const int ro = r * W_;
            if (vm) { Ba0 = p1[ro + gxm]; Bb0 = p2[ro + gxm]; }
            if (vh) { Ba1 = p1[ro + gxh]; Bb1 = p2[ro + gxh]; }
        }
    };
    auto storeA = [&](int buf) {
        rowbuf[w][buf][lane] = make_float2(Aa0, Ab0);
        if (lane < 10) rowbuf[w][buf][64 + lane] = make_float2(Aa1, Ab1);
    };
    auto storeB = [&](int buf) {
        rowbuf[w][buf][lane] = make_float2(Ba0, Bb0);
        if (lane < 10) rowbuf[w][buf][64 + lane] = make_float2(Ba1, Bb1);
    };

    // 11 pending output rows x 5 conv fields; all indices fold to constants
    // under the fully-unrolled pair loop.
    float acc[11][5];
    #pragma unroll
    for (int s = 0; s < 11; ++s)
        #pragma unroll
        for (int f = 0; f < 5; ++f) acc[s][f] = 0.f;

    float psum = 0.f;

    auto dorow = [&](int i, int buf) {
        // Horizontal 11-tap pass over 5 fields from LDS buffer `buf`.
        float s1 = 0.f, s2 = 0.f, s11 = 0.f, s22 = 0.f, s12 = 0.f;
        #pragma unroll
        for (int t = 0; t < 11; ++t) {
            const float2 v = rowbuf[w][buf][lane + t];
            const float ga = G[t] * v.x;
            const float gb = G[t] * v.y;
            s1 += ga;
            s2 += gb;
            s11 = fmaf(ga, v.x, s11);
            s22 = fmaf(gb, v.y, s22);
            s12 = fmaf(ga, v.y, s12);
        }
        // Vertical accumulation into the 11 pending outputs (static slots).
        const int sl = i % 11;
        #pragma unroll
        for (int m = 0; m < 11; ++m) {
            const int s = (sl + m) % 11;
            const float gw = G[10 - m];
            acc[s][0] = fmaf(gw, s1,  acc[s][0]);
            acc[s][1] = fmaf(gw, s2,  acc[s][1]);
            acc[s][2] = fmaf(gw, s11, acc[s][2]);
            acc[s][3] = fmaf(gw, s22, acc[s][3]);
            acc[s][4] = fmaf(gw, s12, acc[s][4]);
        }
        // Output row o = y0 + i - 10 completes in slot sl at i >= 10.
        if (i >= 10) {
            const float mu1 = acc[sl][0], mu2 = acc[sl][1];
            const float x11 = acc[sl][2], x22 = acc[sl][3], x12 = acc[sl][4];
            const float mu1s = mu1 * mu1, mu2s = mu2 * mu2, mu12 = mu1 * mu2;
            const float num = (2.f * mu12 + 1e-4f) * (2.f * (x12 - mu12) + 9e-4f) + 1e-5f;
            const float den = (mu1s + mu2s + 1e-4f)
                            * ((x11 - mu1s) + (x22 - mu2s) + 9e-4f) + 1e-5f;
            psum += __fdividef(num, den);
        }
        // Slot recycled for output o+11: always reset.
        #pragma unroll
        for (int f = 0; f < 5; ++f) acc[sl][f] = 0.f;
    };

    // Prologue: rows 0,1 (input rows y0-5, y0-4) -> buffers 0,1.
    loadA(y0 - 5);
    loadB(y0 - 4);
    storeA(0);
    storeB(1);
    FENCE();

    #pragma unroll
    for (int p = 0; p < NPAIR; ++p) {
        const int i0 = 2 * p;
        // Prefetch the NEXT pair's rows (~640 VALU cycles of cover below).
        if (p < NPAIR - 1) {
            loadA(y0 - 5 + i0 + 2);
            loadB(y0 - 5 + i0 + 3);
        }
        dorow(i0,     i0 & 3);
        dorow(i0 + 1, (i0 + 1) & 3);
        // Stage the prefetched pair into the other buffer pair.
        if (p < NPAIR - 1) {
            storeA((i0 + 2) & 3);
            storeB((i0 + 3) & 3);
        }
        FENCE();   // no DS op crosses pairs (hw DS pipe in-order per wave)
    }

    // Wave reduce -> block reduce -> one atomic; last block finalizes (no
    // second kernel launch).
    #pragma unroll
    for (int off = 32; off > 0; off >>= 1) psum += __shfl_xor(psum, off, 64);
    if (lane == 0) blksum[w] = psum;
    __syncthreads();
    if (tid == 0) {
        atomicAdd(accum, blksum[0] + blksum[1] + blksum[2] + blksum[3]);
        __threadfence();
        const unsigned int done = atomicAdd(cnt, 1u);
        if (done == NBLK - 1) {
            const float tot = atomicAdd(accum, 0.f);  // device-scope read of final sum
            out[0] = 1.0f - tot * (1.0f / 6291456.0f); // B*C*H*MW
        }
    }
}

extern "C" void kernel_launch(void* const* d_in, const int* in_sizes, int n_in,
                              void* d_out, int out_size, void* d_ws, size_t ws_size,
                              hipStream_t stream) {
    const float* img1 = (const float*)d_in[0];
    const float* img2 = (const float*)d_in[1];
    const int*   pos  = (const int*)d_in[2];
    float* out = (float*)d_out;
    float*        acc = (float*)d_ws;
    unsigned int* cnt = (unsigned int*)((char*)d_ws + sizeof(float));

    hipMemsetAsync(d_ws, 0, 2 * sizeof(float), stream);

    // 48 (b,ch) images x 32 row strips; each block = 4 waves = 4 column strips.
    ssim_main<<<NBLK, 256, 0, stream>>>(img1, img2, pos, acc, cnt, out);
}

// Round 7
// 70.322 us; speedup vs baseline: 1.7031x; 1.7031x over previous
//
#include <hip/hip_runtime.h>

// Problem constants (fixed by setup_inputs).
#define B_     16
#define C_     3
#define H_     512
#define W_     1024
#define MW     256         // mask_width
#define RS     12          // output rows per strip
#define NSTRIP 43          // 43*12 = 516 >= 512 (last strip ragged)
#define NIN    (RS + 10)   // 22 input rows streamed per strip

#define FENCE() do { __builtin_amdgcn_sched_barrier(0); \
                     __builtin_amdgcn_wave_barrier();   \
                     __builtin_amdgcn_sched_barrier(0); } while (0)

__global__ __launch_bounds__(256) void ssim_main(const float* __restrict__ img1,
                                                 const float* __restrict__ img2,
                                                 const int*   __restrict__ mask_pos,
                                                 float*       __restrict__ accum) {
    // Gaussian weights = float64 exp/normalize, precomputed to float literals.
    constexpr float G[11] = {
        0.00102838f, 0.00759876f, 0.03600077f, 0.10936070f, 0.21300553f,
        0.26601173f, 0.21300553f, 0.10936070f, 0.03600077f, 0.00759876f,
        0.00102838f };

    // Per-wave double-buffered 74-col {u=x+y, v=x-y} row ring. ~5 KB total.
    __shared__ float2 rowbuf[4][2][80];
    __shared__ float  blksum[4];

    const int tid  = threadIdx.x;
    const int w    = tid >> 6;
    const int lane = tid & 63;

    const int blk   = blockIdx.x;
    const int bc    = blk / NSTRIP;      // (b,ch) 0..47
    const int strip = blk - bc * NSTRIP; // row strip 0..42
    const int b     = bc / 3;

    int s0 = mask_pos[b];
    s0 = min(max(s0, 0), W_ - MW);

    const float* __restrict__ p1 = img1 + (size_t)bc * (H_ * W_);
    const float* __restrict__ p2 = img2 + (size_t)bc * (H_ * W_);

    const int y0  = strip * RS;
    const int sx0 = w << 6;              // column strip base within crop
    const int cxm = sx0 - 5 + lane;      // main staged column (crop coords)
    const int cxh = sx0 + 59 + lane;     // halo staged column (lane < 10)
    const bool vm = (cxm >= 0) && (cxm < MW);
    const bool vh = (lane < 10) && (cxh < MW);
    const int gxm = s0 + cxm;
    const int gxh = s0 + cxh;

    // Single in-flight prefetch register set (distance 1), holding u,v.
    float pu0, pv0, pu1, pv1;
    auto loadrow = [&](int r) {
        pu0 = pv0 = pu1 = pv1 = 0.f;
        if (r >= 0 && r < H_) {          // wave-uniform branch
            const int ro = r * W_;
            if (vm) {
                const float a = p1[ro + gxm], bb = p2[ro + gxm];
                pu0 = a + bb; pv0 = a - bb;
            }
            if (vh) {
                const float a = p1[ro + gxh], bb = p2[ro + gxh];
                pu1 = a + bb; pv1 = a - bb;
            }
        }
    };

    // 11 pending output rows x 4 conv fields {mu_p, mu_m, Suu, Svv};
    // indices static under unroll-11.
    float acc[11][4];
    #pragma unroll
    for (int s = 0; s < 11; ++s)
        #pragma unroll
        for (int f = 0; f < 4; ++f) acc[s][f] = 0.f;

    float psum = 0.f;
    int cur = 0;                         // runtime LDS parity (LDS, not VGPR array)

    // Prologue: stage streamed row 0 (input row y0-5) into parity 0.
    loadrow(y0 - 5);
    rowbuf[w][0][lane] = make_float2(pu0, pv0);
    if (lane < 10) rowbuf[w][0][64 + lane] = make_float2(pu1, pv1);
    FENCE();

    for (int ii = 0; ii < NIN; ii += 11) {
        #pragma unroll
        for (int j = 0; j < 11; ++j) {
            const int i = ii + j;        // streamed row index 0..21
            const bool notlast = (i + 1 < NIN);

            // Prefetch row i+1 into registers (hidden under this row's math).
            if (notlast) loadrow(y0 - 4 + i);

            // Horizontal 11-tap pass over 4 fields from LDS buffer `cur`.
            float su = 0.f, sv = 0.f, suu = 0.f, svv = 0.f;
            #pragma unroll
            for (int t = 0; t < 11; ++t) {
                const float2 q = rowbuf[w][cur][lane + t];
                const float gu = G[t] * q.x;
                const float gv = G[t] * q.y;
                su += gu;
                sv += gv;
                suu = fmaf(gu, q.x, suu);
                svv = fmaf(gv, q.y, svv);
            }

            // Vertical accumulation into the 11 pending outputs (static slots).
            #pragma unroll
            for (int m = 0; m < 11; ++m) {
                const int s = (j + m) % 11;
                const float gw = G[10 - m];
                acc[s][0] = fmaf(gw, su,  acc[s][0]);
                acc[s][1] = fmaf(gw, sv,  acc[s][1]);
                acc[s][2] = fmaf(gw, suu, acc[s][2]);
                acc[s][3] = fmaf(gw, svv, acc[s][3]);
            }

            // Output row o = y0 + i - 10 completes in slot j at i >= 10.
            if (i >= 10) {
                const int o = y0 + i - 10;
                if (o < H_) {            // ragged last strip guard
                    const float mup = acc[j][0], mum = acc[j][1];
                    const float Suu = acc[j][2], Svv = acc[j][3];
                    const float A  = mup * mup, Bq = mum * mum;
                    const float mu_sq_sum = 0.5f * (A + Bq);    // mu1^2 + mu2^2
                    const float mu_cross2 = 0.5f * (A - Bq);    // 2*mu1*mu2
                    const float e_sum     = 0.5f * (Suu + Svv); // Exx + Eyy
                    const float e_cross2  = 0.5f * (Suu - Svv); // 2*Exy
                    const float sig_sum = e_sum - mu_sq_sum;    // sig1 + sig2
                    const float sig12_2 = e_cross2 - mu_cross2; // 2*sig12
                    const float num = (mu_cross2 + 1e-4f) * (sig12_2 + 9e-4f) + 1e-5f;
                    const float den = (mu_sq_sum + 1e-4f) * (sig_sum + 9e-4f) + 1e-5f;
                    psum += __fdividef(num, den);
                }
            }
            // Slot j recycled: always reset.
            #pragma unroll
            for (int f = 0; f < 4; ++f) acc[j][f] = 0.f;

            // Stage prefetched row i+1 into the other buffer.
            if (notlast) {
                rowbuf[w][cur ^ 1][lane] = make_float2(pu0, pv0);
                if (lane < 10) rowbuf[w][cur ^ 1][64 + lane] = make_float2(pu1, pv1);
            }
            cur ^= 1;
            // Fence: no DS op crosses iterations (hw DS pipe in-order per wave).
            FENCE();
        }
    }

    // Wave reduce -> block reduce -> one atomic per block (2064 total).
    #pragma unroll
    for (int off = 32; off > 0; off >>= 1) psum += __shfl_xor(psum, off, 64);
    if (lane == 0) blksum[w] = psum;
    __syncthreads();
    if (tid == 0) {
        atomicAdd(accum, blksum[0] + blksum[1] + blksum[2] + blksum[3]);
    }
}

__global__ void ssim_final(const float* __restrict__ accum, float* __restrict__ out) {
    out[0] = 1.0f - accum[0] * (1.0f / 6291456.0f);  // B*C*H*MW = 16*3*512*256
}

extern "C" void kernel_launch(void* const* d_in, const int* in_sizes, int n_in,
                              void* d_out, int out_size, void* d_ws, size_t ws_size,
                              hipStream_t stream) {
    const float* img1 = (const float*)d_in[0];
    const float* img2 = (const float*)d_in[1];
    const int*   pos  = (const int*)d_in[2];
    float* out = (float*)d_out;
    float* acc = (float*)d_ws;

    hipMemsetAsync(acc, 0, sizeof(float), stream);

    // 48 (b,ch) images x 43 row strips; each block = 4 waves = 4 column strips.
    ssim_main<<<B_ * C_ * NSTRIP, 256, 0, stream>>>(img1, img2, pos, acc);
    ssim_final<<<1, 1, 0, stream>>>(acc, out);
}

// Round 8
// 52.417 us; speedup vs baseline: 2.2849x; 1.3416x over previous
//
#include <hip/hip_runtime.h>

// Problem constants (fixed by setup_inputs).
#define B_     16
#define C_     3
#define H_     512
#define W_     1024
#define MW     256         // mask_width
#define RS     12          // output rows per strip
#define NSTRIP 43          // 43*12 = 516 >= 512 (last strip ragged)
#define NIN    (RS + 10)   // 22 input rows streamed per strip

#define FENCE() do { __builtin_amdgcn_sched_barrier(0); \
                     __builtin_amdgcn_wave_barrier();   \
                     __builtin_amdgcn_sched_barrier(0); } while (0)

__global__ __launch_bounds__(256) void ssim_main(const float* __restrict__ img1,
                                                 const float* __restrict__ img2,
                                                 const int*   __restrict__ mask_pos,
                                                 float*       __restrict__ accum) {
    // Gaussian weights = float64 exp/normalize, precomputed to float literals.
    constexpr float G[11] = {
        0.00102838f, 0.00759876f, 0.03600077f, 0.10936070f, 0.21300553f,
        0.26601173f, 0.21300553f, 0.10936070f, 0.03600077f, 0.00759876f,
        0.00102838f };

    // Per-wave double-buffered 74-col {u=x+y, v=x-y} row ring. ~5 KB total.
    __shared__ float2 rowbuf[4][2][80];
    __shared__ float  blksum[4];

    const int tid  = threadIdx.x;
    const int w    = tid >> 6;
    const int lane = tid & 63;

    const int blk   = blockIdx.x;
    const int bc    = blk / NSTRIP;      // (b,ch) 0..47
    const int strip = blk - bc * NSTRIP; // row strip 0..42
    const int b     = bc / 3;

    int s0 = mask_pos[b];
    s0 = min(max(s0, 0), W_ - MW);

    const float* __restrict__ p1 = img1 + (size_t)bc * (H_ * W_);
    const float* __restrict__ p2 = img2 + (size_t)bc * (H_ * W_);

    const int y0  = strip * RS;
    const int sx0 = w << 6;              // column strip base within crop
    const int cxm = sx0 - 5 + lane;      // main staged column (crop coords)
    const int cxh = sx0 + 59 + lane;     // halo staged column (lane < 10)
    const bool vm = (cxm >= 0) && (cxm < MW);
    const bool vh = (lane < 10) && (cxh < MW);
    const int gxm = s0 + cxm;
    const int gxh = s0 + cxh;

    // Single in-flight prefetch register set (distance 1) — RAW values only.
    // The u/v transform happens AT THE STORE (bottom of iteration) so the
    // vmcnt wait stays at the ds_write, hidden under this row's compute.
    float pa0, pb0, pa1, pb1;
    auto loadrow = [&](int r) {
        pa0 = pb0 = pa1 = pb1 = 0.f;
        if (r >= 0 && r < H_) {          // wave-uniform branch
            const int ro = r * W_;
            if (vm) { pa0 = p1[ro + gxm]; pb0 = p2[ro + gxm]; }
            if (vh) { pa1 = p1[ro + gxh]; pb1 = p2[ro + gxh]; }
        }
    };

    // 11 pending output rows x 4 conv fields {mu_p, mu_m, Suu, Svv};
    // indices static under unroll-11.
    float acc[11][4];
    #pragma unroll
    for (int s = 0; s < 11; ++s)
        #pragma unroll
        for (int f = 0; f < 4; ++f) acc[s][f] = 0.f;

    float psum = 0.f;
    int cur = 0;                         // runtime LDS parity (LDS, not VGPR array)

    // Prologue: stage streamed row 0 (input row y0-5) into parity 0.
    loadrow(y0 - 5);
    rowbuf[w][0][lane] = make_float2(pa0 + pb0, pa0 - pb0);
    if (lane < 10) rowbuf[w][0][64 + lane] = make_float2(pa1 + pb1, pa1 - pb1);
    FENCE();

    for (int ii = 0; ii < NIN; ii += 11) {
        #pragma unroll
        for (int j = 0; j < 11; ++j) {
            const int i = ii + j;        // streamed row index 0..21
            const bool notlast = (i + 1 < NIN);

            // Prefetch row i+1 into registers (hidden under this row's math).
            if (notlast) loadrow(y0 - 4 + i);

            // Horizontal 11-tap pass over 4 fields from LDS buffer `cur`.
            float su = 0.f, sv = 0.f, suu = 0.f, svv = 0.f;
            #pragma unroll
            for (int t = 0; t < 11; ++t) {
                const float2 q = rowbuf[w][cur][lane + t];
                const float gu = G[t] * q.x;
                const float gv = G[t] * q.y;
                su += gu;
                sv += gv;
                suu = fmaf(gu, q.x, suu);
                svv = fmaf(gv, q.y, svv);
            }

            // Vertical accumulation into the 11 pending outputs (static slots).
            #pragma unroll
            for (int m = 0; m < 11; ++m) {
                const int s = (j + m) % 11;
                const float gw = G[10 - m];
                acc[s][0] = fmaf(gw, su,  acc[s][0]);
                acc[s][1] = fmaf(gw, sv,  acc[s][1]);
                acc[s][2] = fmaf(gw, suu, acc[s][2]);
                acc[s][3] = fmaf(gw, svv, acc[s][3]);
            }

            // Output row o = y0 + i - 10 completes in slot j at i >= 10.
            if (i >= 10) {
                const int o = y0 + i - 10;
                if (o < H_) {            // ragged last strip guard
                    const float mup = acc[j][0], mum = acc[j][1];
                    const float Suu = acc[j][2], Svv = acc[j][3];
                    const float A  = mup * mup, Bq = mum * mum;
                    const float mu_sq_sum = 0.5f * (A + Bq);    // mu1^2 + mu2^2
                    const float mu_cross2 = 0.5f * (A - Bq);    // 2*mu1*mu2
                    const float e_sum     = 0.5f * (Suu + Svv); // Exx + Eyy
                    const float e_cross2  = 0.5f * (Suu - Svv); // 2*Exy
                    const float sig_sum = e_sum - mu_sq_sum;    // sig1 + sig2
                    const float sig12_2 = e_cross2 - mu_cross2; // 2*sig12
                    const float num = (mu_cross2 + 1e-4f) * (sig12_2 + 9e-4f) + 1e-5f;
                    const float den = (mu_sq_sum + 1e-4f) * (sig_sum + 9e-4f) + 1e-5f;
                    psum += __fdividef(num, den);
                }
            }
            // Slot j recycled: always reset.
            #pragma unroll
            for (int f = 0; f < 4; ++f) acc[j][f] = 0.f;

            // Stage prefetched row i+1: u/v computed INLINE at the store, so
            // the first use of the loads (and the vmcnt wait) is here.
            if (notlast) {
                rowbuf[w][cur ^ 1][lane] = make_float2(pa0 + pb0, pa0 - pb0);
                if (lane < 10)
                    rowbuf[w][cur ^ 1][64 + lane] = make_float2(pa1 + pb1, pa1 - pb1);
            }
            cur ^= 1;
            // Fence: no DS op crosses iterations (hw DS pipe in-order per wave).
            FENCE();
        }
    }

    // Wave reduce -> block reduce -> one atomic per block (2064 total).
    #pragma unroll
    for (int off = 32; off > 0; off >>= 1) psum += __shfl_xor(psum, off, 64);
    if (lane == 0) blksum[w] = psum;
    __syncthreads();
    if (tid == 0) {
        atomicAdd(accum, blksum[0] + blksum[1] + blksum[2] + blksum[3]);
    }
}

__global__ void ssim_final(const float* __restrict__ accum, float* __restrict__ out) {
    out[0] = 1.0f - accum[0] * (1.0f / 6291456.0f);  // B*C*H*MW = 16*3*512*256
}

extern "C" void kernel_launch(void* const* d_in, const int* in_sizes, int n_in,
                              void* d_out, int out_size, void* d_ws, size_t ws_size,
                              hipStream_t stream) {
    const float* img1 = (const float*)d_in[0];
    const float* img2 = (const float*)d_in[1];
    const int*   pos  = (const int*)d_in[2];
    float* out = (float*)d_out;
    float* acc = (float*)d_ws;

    hipMemsetAsync(acc, 0, sizeof(float), stream);

    // 48 (b,ch) images x 43 row strips; each block = 4 waves = 4 column strips.
    ssim_main<<<B_ * C_ * NSTRIP, 256, 0, stream>>>(img1, img2, pos, acc);
    ssim_final<<<1, 1, 0, stream>>>(acc, out);
}

// Round 9
// 48.298 us; speedup vs baseline: 2.4798x; 1.0853x over previous
//
#include <hip/hip_runtime.h>

// Problem constants (fixed by setup_inputs).
#define B_     16
#define C_     3
#define H_     512
#define W_     1024
#define MW     256         // mask_width
#define RS     16          // output rows per strip
#define NSTRIP 32          // 32*16 = 512 exact (no ragged strip)
#define NIN    (RS + 10)   // 26 input rows streamed per strip

// Memory fence only: wave_barrier pins all DS/VMEM ordering (IR + MIR) but
// lets pure VALU flow across iterations (software pipelining).
#define FENCE() __builtin_amdgcn_wave_barrier()

__global__ __launch_bounds__(256) void ssim_main(const float* __restrict__ img1,
                                                 const float* __restrict__ img2,
                                                 const int*   __restrict__ mask_pos,
                                                 float*       __restrict__ accum) {
    // Gaussian weights = float64 exp/normalize, precomputed to float literals.
    constexpr float G[11] = {
        0.00102838f, 0.00759876f, 0.03600077f, 0.10936070f, 0.21300553f,
        0.26601173f, 0.21300553f, 0.10936070f, 0.03600077f, 0.00759876f,
        0.00102838f };

    // Per-wave double-buffered 74-col {u=x+y, v=x-y} row ring. ~5 KB total.
    __shared__ float2 rowbuf[4][2][80];
    __shared__ float  blksum[4];

    const int tid  = threadIdx.x;
    const int w    = tid >> 6;
    const int lane = tid & 63;

    const int blk   = blockIdx.x;
    const int strip = blk & (NSTRIP - 1);
    const int bc    = blk >> 5;          // (b,ch) 0..47
    const int b     = bc / 3;

    int s0 = mask_pos[b];
    s0 = min(max(s0, 0), W_ - MW);

    const float* __restrict__ p1 = img1 + (size_t)bc * (H_ * W_);
    const float* __restrict__ p2 = img2 + (size_t)bc * (H_ * W_);

    const int y0  = strip * RS;
    const int sx0 = w << 6;              // column strip base within crop
    const int cxm = sx0 - 5 + lane;      // main staged column (crop coords)
    const int cxh = sx0 + 59 + lane;     // halo staged column (lane < 10)
    const bool vm = (cxm >= 0) && (cxm < MW);
    const bool vh = (lane < 10) && (cxh < MW);
    const int gxm = s0 + cxm;
    const int gxh = s0 + cxh;

    // Single in-flight prefetch register set (distance 1) — RAW values only.
    // u/v transform happens AT THE STORE (bottom of iteration) so the vmcnt
    // wait stays at the ds_write, hidden under this row's compute.
    float pa0, pb0, pa1, pb1;
    auto loadrow = [&](int r) {
        pa0 = pb0 = pa1 = pb1 = 0.f;
        if (r >= 0 && r < H_) {          // wave-uniform branch
            const int ro = r * W_;
            if (vm) { pa0 = p1[ro + gxm]; pb0 = p2[ro + gxm]; }
            if (vh) { pa1 = p1[ro + gxh]; pb1 = p2[ro + gxh]; }
        }
    };

    // 11 pending output rows x 4 conv fields {mu_p, mu_m, Suu, Svv};
    // slot index `sl` is compile-time at every call site.
    float acc[11][4];
    #pragma unroll
    for (int s = 0; s < 11; ++s)
        #pragma unroll
        for (int f = 0; f < 4; ++f) acc[s][f] = 0.f;

    float psum = 0.f;
    int cur = 0;                         // runtime LDS parity (LDS, not VGPR array)

    auto dorow = [&](int i, int sl) {
        const bool notlast = (i + 1 < NIN);

        // Prefetch row i+1 into registers (hidden under this row's math).
        if (notlast) loadrow(y0 - 4 + i);

        // Horizontal 11-tap pass over 4 fields from LDS buffer `cur`.
        float su = 0.f, sv = 0.f, suu = 0.f, svv = 0.f;
        #pragma unroll
        for (int t = 0; t < 11; ++t) {
            const float2 q = rowbuf[w][cur][lane + t];
            const float gu = G[t] * q.x;
            const float gv = G[t] * q.y;
            su += gu;
            sv += gv;
            suu = fmaf(gu, q.x, suu);
            svv = fmaf(gv, q.y, svv);
        }

        // Vertical accumulation into the 11 pending outputs (static slots).
        #pragma unroll
        for (int m = 0; m < 11; ++m) {
            const int s = (sl + m) % 11;
            const float gw = G[10 - m];
            acc[s][0] = fmaf(gw, su,  acc[s][0]);
            acc[s][1] = fmaf(gw, sv,  acc[s][1]);
            acc[s][2] = fmaf(gw, suu, acc[s][2]);
            acc[s][3] = fmaf(gw, svv, acc[s][3]);
        }

        // Output row o = y0 + i - 10 completes in slot sl at i >= 10.
        if (i >= 10) {
            const float mup = acc[sl][0], mum = acc[sl][1];
            const float Suu = acc[sl][2], Svv = acc[sl][3];
            const float A  = mup * mup, Bq = mum * mum;
            const float mu_sq_sum = 0.5f * (A + Bq);    // mu1^2 + mu2^2
            const float mu_cross2 = 0.5f * (A - Bq);    // 2*mu1*mu2
            const float e_sum     = 0.5f * (Suu + Svv); // Exx + Eyy
            const float e_cross2  = 0.5f * (Suu - Svv); // 2*Exy
            const float sig_sum = e_sum - mu_sq_sum;    // sig1 + sig2
            const float sig12_2 = e_cross2 - mu_cross2; // 2*sig12
            const float num = (mu_cross2 + 1e-4f) * (sig12_2 + 9e-4f) + 1e-5f;
            const float den = (mu_sq_sum + 1e-4f) * (sig_sum + 9e-4f) + 1e-5f;
            psum += __fdividef(num, den);
        }
        // Slot sl recycled: always reset.
        #pragma unroll
        for (int f = 0; f < 4; ++f) acc[sl][f] = 0.f;

        // Stage prefetched row i+1: u/v computed INLINE at the store, so the
        // first use of the loads (and the vmcnt wait) is here.
        if (notlast) {
            rowbuf[w][cur ^ 1][lane] = make_float2(pa0 + pb0, pa0 - pb0);
            if (lane < 10)
                rowbuf[w][cur ^ 1][64 + lane] = make_float2(pa1 + pb1, pa1 - pb1);
        }
        cur ^= 1;
        // Memory-only fence: DS/VMEM may not cross; VALU may.
        FENCE();
    };

    // Prologue: stage streamed row 0 (input row y0-5) into parity 0.
    loadrow(y0 - 5);
    rowbuf[w][0][lane] = make_float2(pa0 + pb0, pa0 - pb0);
    if (lane < 10) rowbuf[w][0][64 + lane] = make_float2(pa1 + pb1, pa1 - pb1);
    FENCE();

    // Main 22 rows (2 x 11 so sl stays compile-time), then 4-row tail
    // (22 % 11 == 0, so tail slot == j, still compile-time).
    for (int ii = 0; ii < 22; ii += 11) {
        #pragma unroll
        for (int j = 0; j < 11; ++j) dorow(ii + j, j);
    }
    #pragma unroll
    for (int j = 0; j < 4; ++j) dorow(22 + j, j);

    // Wave reduce -> block reduce -> one atomic per block (1536 total).
    #pragma unroll
    for (int off = 32; off > 0; off >>= 1) psum += __shfl_xor(psum, off, 64);
    if (lane == 0) blksum[w] = psum;
    __syncthreads();
    if (tid == 0) {
        atomicAdd(accum, blksum[0] + blksum[1] + blksum[2] + blksum[3]);
    }
}

__global__ void ssim_final(const float* __restrict__ accum, float* __restrict__ out) {
    out[0] = 1.0f - accum[0] * (1.0f / 6291456.0f);  // B*C*H*MW = 16*3*512*256
}

extern "C" void kernel_launch(void* const* d_in, const int* in_sizes, int n_in,
                              void* d_out, int out_size, void* d_ws, size_t ws_size,
                              hipStream_t stream) {
    const float* img1 = (const float*)d_in[0];
    const float* img2 = (const float*)d_in[1];
    const int*   pos  = (const int*)d_in[2];
    float* out = (float*)d_out;
    float* acc = (float*)d_ws;

    hipMemsetAsync(acc, 0, sizeof(float), stream);

    // 48 (b,ch) images x 32 row strips; each block = 4 waves = 4 column strips.
    ssim_main<<<B_ * C_ * NSTRIP, 256, 0, stream>>>(img1, img2, pos, acc);
    ssim_final<<<1, 1, 0, stream>>>(acc, out);
}

// Round 10
// 46.924 us; speedup vs baseline: 2.5524x; 1.0293x over previous
//
#include <hip/hip_runtime.h>

// Problem constants (fixed by setup_inputs).
#define B_     16
#define C_     3
#define H_     512
#define W_     1024
#define MW     256         // mask_width
#define RS     16          // output rows per strip
#define NSTRIP 32          // 32*16 = 512 exact (no ragged strip)
#define NIN    (RS + 10)   // 26 input rows streamed per strip

// Memory fence only: wave_barrier pins all DS/VMEM ordering (IR + MIR) but
// lets pure VALU flow across iterations (software pipelining).
#define FENCE() __builtin_amdgcn_wave_barrier()

__global__ __launch_bounds__(256) void ssim_main(const float* __restrict__ img1,
                                                 const float* __restrict__ img2,
                                                 const int*   __restrict__ mask_pos,
                                                 float*       __restrict__ accum) {
    // Gaussian weights = float64 exp/normalize, precomputed to float literals.
    constexpr float G[11] = {
        0.00102838f, 0.00759876f, 0.03600077f, 0.10936070f, 0.21300553f,
        0.26601173f, 0.21300553f, 0.10936070f, 0.03600077f, 0.00759876f,
        0.00102838f };

    // Per-wave double-buffered 74-col {u=x+y, v=x-y} row ring. ~5 KB total.
    __shared__ float2 rowbuf[4][2][80];
    __shared__ float  blksum[4];

    const int tid  = threadIdx.x;
    const int w    = tid >> 6;
    const int lane = tid & 63;

    // L2-locality remap: dispatch round-robins blockIdx over the 8 XCDs, so
    // give each XCD 6 complete (b,ch) images with sequential strips. Adjacent
    // strips (which share 10 halo rows) then hit the same XCD's L2.
    // Bijection: 1536 = 8 xcd * (6 images * 32 strips).
    const int d     = blockIdx.x;
    const int xcd   = d & 7;
    const int q     = d >> 3;            // 0..191 within XCD
    const int bc    = xcd * 6 + (q >> 5);// (b,ch) 0..47
    const int strip = q & 31;            // row strip 0..31
    const int b     = bc / 3;

    int s0 = mask_pos[b];
    s0 = min(max(s0, 0), W_ - MW);

    const float* __restrict__ p1 = img1 + (size_t)bc * (H_ * W_);
    const float* __restrict__ p2 = img2 + (size_t)bc * (H_ * W_);

    const int y0  = strip * RS;
    const int sx0 = w << 6;              // column strip base within crop
    const int cxm = sx0 - 5 + lane;      // main staged column (crop coords)
    const int cxh = sx0 + 59 + lane;     // halo staged column (lane < 10)
    const bool vm = (cxm >= 0) && (cxm < MW);
    const bool vh = (lane < 10) && (cxh < MW);
    const int gxm = s0 + cxm;
    const int gxh = s0 + cxh;

    // Single in-flight prefetch register set (distance 1) — RAW values only.
    // u/v transform happens AT THE STORE (bottom of iteration) so the vmcnt
    // wait stays at the ds_write, hidden under this row's compute.
    float pa0, pb0, pa1, pb1;
    auto loadrow = [&](int r) {
        pa0 = pb0 = pa1 = pb1 = 0.f;
        if (r >= 0 && r < H_) {          // wave-uniform branch
            const int ro = r * W_;
            if (vm) { pa0 = p1[ro + gxm]; pb0 = p2[ro + gxm]; }
            if (vh) { pa1 = p1[ro + gxh]; pb1 = p2[ro + gxh]; }
        }
    };

    // 11 pending output rows x 4 conv fields {mu_p, mu_m, Suu, Svv};
    // slot index `sl` is compile-time at every call site.
    float acc[11][4];
    #pragma unroll
    for (int s = 0; s < 11; ++s)
        #pragma unroll
        for (int f = 0; f < 4; ++f) acc[s][f] = 0.f;

    float psum = 0.f;
    int cur = 0;                         // runtime LDS parity (LDS, not VGPR array)

    auto dorow = [&](int i, int sl) {
        const bool notlast = (i + 1 < NIN);

        // Prefetch row i+1 into registers (hidden under this row's math).
        if (notlast) loadrow(y0 - 4 + i);

        // Horizontal 11-tap pass over 4 fields from LDS buffer `cur`.
        float su = 0.f, sv = 0.f, suu = 0.f, svv = 0.f;
        #pragma unroll
        for (int t = 0; t < 11; ++t) {
            const float2 q2 = rowbuf[w][cur][lane + t];
            const float gu = G[t] * q2.x;
            const float gv = G[t] * q2.y;
            su += gu;
            sv += gv;
            suu = fmaf(gu, q2.x, suu);
            svv = fmaf(gv, q2.y, svv);
        }

        // Vertical accumulation into the 11 pending outputs (static slots).
        #pragma unroll
        for (int m = 0; m < 11; ++m) {
            const int s = (sl + m) % 11;
            const float gw = G[10 - m];
            acc[s][0] = fmaf(gw, su,  acc[s][0]);
            acc[s][1] = fmaf(gw, sv,  acc[s][1]);
            acc[s][2] = fmaf(gw, suu, acc[s][2]);
            acc[s][3] = fmaf(gw, svv, acc[s][3]);
        }

        // Output row o = y0 + i - 10 completes in slot sl at i >= 10.
        if (i >= 10) {
            const float mup = acc[sl][0], mum = acc[sl][1];
            const float Suu = acc[sl][2], Svv = acc[sl][3];
            const float A  = mup * mup, Bq = mum * mum;
            const float mu_sq_sum = 0.5f * (A + Bq);    // mu1^2 + mu2^2
            const float mu_cross2 = 0.5f * (A - Bq);    // 2*mu1*mu2
            const float e_sum     = 0.5f * (Suu + Svv); // Exx + Eyy
            const float e_cross2  = 0.5f * (Suu - Svv); // 2*Exy
            const float sig_sum = e_sum - mu_sq_sum;    // sig1 + sig2
            const float sig12_2 = e_cross2 - mu_cross2; // 2*sig12
            const float num = (mu_cross2 + 1e-4f) * (sig12_2 + 9e-4f) + 1e-5f;
            const float den = (mu_sq_sum + 1e-4f) * (sig_sum + 9e-4f) + 1e-5f;
            psum += __fdividef(num, den);
        }
        // Slot sl recycled: always reset.
        #pragma unroll
        for (int f = 0; f < 4; ++f) acc[sl][f] = 0.f;

        // Stage prefetched row i+1: u/v computed INLINE at the store, so the
        // first use of the loads (and the vmcnt wait) is here.
        if (notlast) {
            rowbuf[w][cur ^ 1][lane] = make_float2(pa0 + pb0, pa0 - pb0);
            if (lane < 10)
                rowbuf[w][cur ^ 1][64 + lane] = make_float2(pa1 + pb1, pa1 - pb1);
        }
        cur ^= 1;
        // Memory-only fence: DS/VMEM may not cross; VALU may.
        FENCE();
    };

    // Prologue: stage streamed row 0 (input row y0-5) into parity 0.
    loadrow(y0 - 5);
    rowbuf[w][0][lane] = make_float2(pa0 + pb0, pa0 - pb0);
    if (lane < 10) rowbuf[w][0][64 + lane] = make_float2(pa1 + pb1, pa1 - pb1);
    FENCE();

    // Main 22 rows (2 x 11 so sl stays compile-time), then 4-row tail
    // (22 % 11 == 0, so tail slot == j, still compile-time).
    for (int ii = 0; ii < 22; ii += 11) {
        #pragma unroll
        for (int j = 0; j < 11; ++j) dorow(ii + j, j);
    }
    #pragma unroll
    for (int j = 0; j < 4; ++j) dorow(22 + j, j);

    // Wave reduce -> block reduce -> one atomic per block (1536 total).
    #pragma unroll
    for (int off = 32; off > 0; off >>= 1) psum += __shfl_xor(psum, off, 64);
    if (lane == 0) blksum[w] = psum;
    __syncthreads();
    if (tid == 0) {
        atomicAdd(accum, blksum[0] + blksum[1] + blksum[2] + blksum[3]);
    }
}

__global__ void ssim_final(const float* __restrict__ accum, float* __restrict__ out) {
    out[0] = 1.0f - accum[0] * (1.0f / 6291456.0f);  // B*C*H*MW = 16*3*512*256
}

extern "C" void kernel_launch(void* const* d_in, const int* in_sizes, int n_in,
                              void* d_out, int out_size, void* d_ws, size_t ws_size,
                              hipStream_t stream) {
    const float* img1 = (const float*)d_in[0];
    const float* img2 = (const float*)d_in[1];
    const int*   pos  = (const int*)d_in[2];
    float* out = (float*)d_out;
    float* acc = (float*)d_ws;

    hipMemsetAsync(acc, 0, sizeof(float), stream);

    // 8 XCDs x 6 images x 32 strips; each block = 4 waves = 4 column strips.
    ssim_main<<<B_ * C_ * NSTRIP, 256, 0, stream>>>(img1, img2, pos, acc);
    ssim_final<<<1, 1, 0, stream>>>(acc, out);
}